// Round 2
// baseline (235.700 us; speedup 1.0000x reference)
//
#include <hip/hip_runtime.h>

// Inverse wavelet transform (Haar):
//   x: [4B, C, H, W] fp32 with B=8, C=64, H=128, W=128
//   out: [B, C, 2H, 2W] fp32
// out[b,c,2i+0,2j+0] = 0.5*(x1 - x2 - x3 + x4)
// out[b,c,2i+0,2j+1] = 0.5*(x1 + x2 - x3 - x4)
// out[b,c,2i+1,2j+0] = 0.5*(x1 - x2 + x3 - x4)
// out[b,c,2i+1,2j+1] = 0.5*(x1 + x2 + x3 + x4)
// where xk = x[(k-1)*B + b, c, i, j].
//
// Pure streaming op: 128 MiB in + 128 MiB out. Memory-bound.
// Each thread: 4x float4 loads (one per quarter), 4x float4 stores.
// All sizes derived at runtime from in_sizes/out_size (defensive: the
// captured launch geometry always matches the passed buffers).

constexpr int H = 128, W = 128;
constexpr int HW = H * W;             // 16384 (per-channel input plane)
constexpr int OUT_ROW = 2 * W;        // 256 floats per output row
constexpr int OUT_PLANE = 4 * HW;     // 65536 floats per (b,c) output plane

__global__ __launch_bounds__(256) void iwt_kernel(const float* __restrict__ x,
                                                  float* __restrict__ out,
                                                  int quarter,   // elems per input quarter
                                                  int total_vec) // threads doing work
{
    int tid = blockIdx.x * blockDim.x + threadIdx.x;
    if (tid >= total_vec) return;

    // tid = ((b*C + c)*H + i)*(W/4) + jv
    int jv = tid & 31;               // W/4 = 32 vec4-columns
    int i  = (tid >> 5) & (H - 1);   // H = 128
    int cb = tid >> 12;              // b*C + c

    int in_off = cb * HW + i * W + (jv << 2);

    const float4 a1 = *reinterpret_cast<const float4*>(x + in_off);
    const float4 a2 = *reinterpret_cast<const float4*>(x + in_off + quarter);
    const float4 a3 = *reinterpret_cast<const float4*>(x + in_off + 2 * quarter);
    const float4 a4 = *reinterpret_cast<const float4*>(x + in_off + 3 * quarter);

    float v1[4] = {a1.x, a1.y, a1.z, a1.w};
    float v2[4] = {a2.x, a2.y, a2.z, a2.w};
    float v3[4] = {a3.x, a3.y, a3.z, a3.w};
    float v4[4] = {a4.x, a4.y, a4.z, a4.w};

    float top[8], bot[8];
#pragma unroll
    for (int k = 0; k < 4; ++k) {
        float s1 = v1[k] * 0.5f;
        float s2 = v2[k] * 0.5f;
        float s3 = v3[k] * 0.5f;
        float s4 = v4[k] * 0.5f;
        top[2 * k + 0] = s1 - s2 - s3 + s4;  // e00
        top[2 * k + 1] = s1 + s2 - s3 - s4;  // e01
        bot[2 * k + 0] = s1 - s2 + s3 - s4;  // e10
        bot[2 * k + 1] = s1 + s2 + s3 + s4;  // e11
    }

    int out_top = cb * OUT_PLANE + (2 * i) * OUT_ROW + (jv << 3);
    int out_bot = out_top + OUT_ROW;

    *reinterpret_cast<float4*>(out + out_top)     = make_float4(top[0], top[1], top[2], top[3]);
    *reinterpret_cast<float4*>(out + out_top + 4) = make_float4(top[4], top[5], top[6], top[7]);
    *reinterpret_cast<float4*>(out + out_bot)     = make_float4(bot[0], bot[1], bot[2], bot[3]);
    *reinterpret_cast<float4*>(out + out_bot + 4) = make_float4(bot[4], bot[5], bot[6], bot[7]);
}

extern "C" void kernel_launch(void* const* d_in, const int* in_sizes, int n_in,
                              void* d_out, int out_size, void* d_ws, size_t ws_size,
                              hipStream_t stream) {
    const float* x = (const float*)d_in[0];
    float* out = (float*)d_out;

    const int quarter   = in_sizes[0] / 4;   // 8,388,608
    const int total_vec = out_size / 16;     // 16 output floats per thread -> 2,097,152
    const int block = 256;
    const int grid  = (total_vec + block - 1) / block;  // 8192

    iwt_kernel<<<grid, block, 0, stream>>>(x, out, quarter, total_vec);
}

// Round 4
// 227.655 us; speedup vs baseline: 1.0353x; 1.0353x over previous
//
#include <hip/hip_runtime.h>

// Inverse wavelet transform (Haar):
//   x: [4B, C, H, W] fp32 with B=8, C=64, H=128, W=128
//   out: [B, C, 2H, 2W] fp32
//
// Round-3 layout (resubmitted after broker timeout — no result yet):
// one thread per float2 input column-pair.
//   loads : 4x float2 (8 B/lane, contiguous across wave -> 512 B/instr)
//   stores: 2x float4 (16 B/lane, contiguous across wave -> 1 KB/instr,
//           full 128 B cache lines per store instruction)
// Fixes round-2's interleaved stores (16 B written / 32 B stride = partial
// cache lines per instruction), which capped write BW at ~2.4 TB/s.

constexpr int H = 128, W = 128;
constexpr int HW = H * W;             // 16384 (per-channel input plane)
constexpr int OUT_ROW = 2 * W;        // 256 floats per output row
constexpr int OUT_PLANE = 4 * HW;     // 65536 floats per (b,c) output plane

__global__ __launch_bounds__(256) void iwt_kernel(const float* __restrict__ x,
                                                  float* __restrict__ out,
                                                  int quarter,   // elems per input quarter
                                                  int total_vec) // total worker threads
{
    int tid = blockIdx.x * blockDim.x + threadIdx.x;
    if (tid >= total_vec) return;

    // tid = ((b*C + c)*H + i)*(W/2) + jv2
    int jv2 = tid & 63;              // W/2 = 64 float2-columns
    int i   = (tid >> 6) & (H - 1);  // H = 128
    int cb  = tid >> 13;             // b*C + c

    int in_off = cb * HW + i * W + (jv2 << 1);

    const float2 a1 = *reinterpret_cast<const float2*>(x + in_off);
    const float2 a2 = *reinterpret_cast<const float2*>(x + in_off + quarter);
    const float2 a3 = *reinterpret_cast<const float2*>(x + in_off + 2 * quarter);
    const float2 a4 = *reinterpret_cast<const float2*>(x + in_off + 3 * quarter);

    // column 0
    float s1 = a1.x * 0.5f, s2 = a2.x * 0.5f, s3 = a3.x * 0.5f, s4 = a4.x * 0.5f;
    float e00a = s1 - s2 - s3 + s4;
    float e01a = s1 + s2 - s3 - s4;
    float e10a = s1 - s2 + s3 - s4;
    float e11a = s1 + s2 + s3 + s4;
    // column 1
    float t1 = a1.y * 0.5f, t2 = a2.y * 0.5f, t3 = a3.y * 0.5f, t4 = a4.y * 0.5f;
    float e00b = t1 - t2 - t3 + t4;
    float e01b = t1 + t2 - t3 - t4;
    float e10b = t1 - t2 + t3 - t4;
    float e11b = t1 + t2 + t3 + t4;

    int out_top = cb * OUT_PLANE + (2 * i) * OUT_ROW + (jv2 << 2);
    int out_bot = out_top + OUT_ROW;

    *reinterpret_cast<float4*>(out + out_top) = make_float4(e00a, e01a, e00b, e01b);
    *reinterpret_cast<float4*>(out + out_bot) = make_float4(e10a, e11a, e10b, e11b);
}

extern "C" void kernel_launch(void* const* d_in, const int* in_sizes, int n_in,
                              void* d_out, int out_size, void* d_ws, size_t ws_size,
                              hipStream_t stream) {
    const float* x = (const float*)d_in[0];
    float* out = (float*)d_out;

    const int quarter   = in_sizes[0] / 4;   // 8,388,608
    const int total_vec = out_size / 8;      // 8 output floats per thread -> 4,194,304
    const int block = 256;
    const int grid  = (total_vec + block - 1) / block;  // 16384

    iwt_kernel<<<grid, block, 0, stream>>>(x, out, quarter, total_vec);
}